// Round 1
// baseline (115.219 us; speedup 1.0000x reference)
//
#include <hip/hip_runtime.h>

// Problem constants (shapes fixed by reference; N/B derived from in_sizes).
#define F_DIM 128
#define D_DIM 64
#define K_NBR 128

// ---------------------------------------------------------------------------
// Kernel 1: enc[r][d] = sum_f X[r][f] * W[f][d] + b[d]
// One thread per row. W + b staged in LDS (32 KB + 256 B). acc[64] in VGPRs.
// ---------------------------------------------------------------------------
__global__ __launch_bounds__(256) void encode_kernel(
    const float* __restrict__ X, const float* __restrict__ W,
    const float* __restrict__ bias, float* __restrict__ enc, int n)
{
    __shared__ float Ws[F_DIM * D_DIM];
    __shared__ float bs[D_DIM];

    const int t = threadIdx.x;

    // Cooperative load W (8192 floats) as float4: 2048 float4 / 256 threads.
    const float4* Wg = reinterpret_cast<const float4*>(W);
    float4* Wl = reinterpret_cast<float4*>(Ws);
    #pragma unroll
    for (int i = 0; i < (F_DIM * D_DIM / 4) / 256; ++i)
        Wl[i * 256 + t] = Wg[i * 256 + t];
    if (t < D_DIM) bs[t] = bias[t];
    __syncthreads();

    const int r = blockIdx.x * 256 + t;
    if (r >= n) return;

    float acc[D_DIM];
    #pragma unroll
    for (int d = 0; d < D_DIM; ++d) acc[d] = 0.f;

    const float4* xrow = reinterpret_cast<const float4*>(X + (size_t)r * F_DIM);
    for (int f4 = 0; f4 < F_DIM / 4; ++f4) {
        float4 x = xrow[f4];
        #pragma unroll
        for (int j = 0; j < 4; ++j) {
            const float xv = (j == 0) ? x.x : (j == 1) ? x.y : (j == 2) ? x.z : x.w;
            const float4* wrow =
                reinterpret_cast<const float4*>(&Ws[(f4 * 4 + j) * D_DIM]);
            #pragma unroll
            for (int d4 = 0; d4 < D_DIM / 4; ++d4) {
                float4 w = wrow[d4];  // uniform address -> LDS broadcast
                acc[d4 * 4 + 0] += xv * w.x;
                acc[d4 * 4 + 1] += xv * w.y;
                acc[d4 * 4 + 2] += xv * w.z;
                acc[d4 * 4 + 3] += xv * w.w;
            }
        }
    }

    float4* orow = reinterpret_cast<float4*>(enc + (size_t)r * D_DIM);
    #pragma unroll
    for (int d4 = 0; d4 < D_DIM / 4; ++d4) {
        float4 o;
        o.x = acc[d4 * 4 + 0] + bs[d4 * 4 + 0];
        o.y = acc[d4 * 4 + 1] + bs[d4 * 4 + 1];
        o.z = acc[d4 * 4 + 2] + bs[d4 * 4 + 2];
        o.w = acc[d4 * 4 + 3] + bs[d4 * 4 + 3];
        orow[d4] = o;
    }
}

// ---------------------------------------------------------------------------
// Kernel 2: out[b][d] = sum_k values[idx[b]][k] * enc[indices[idx[b]][k]][d]
// One block (256 thr = 4 waves) per seed b. ids/vals staged in LDS.
// Wave w handles k = w, w+4, ...; lane l = d. enc row read = coalesced 256 B.
// ---------------------------------------------------------------------------
__global__ __launch_bounds__(256) void gather_kernel(
    const int* __restrict__ idx, const int* __restrict__ indices,
    const float* __restrict__ values, const float* __restrict__ enc,
    float* __restrict__ out)
{
    __shared__ int   ids[K_NBR];
    __shared__ float vs[K_NBR];
    __shared__ float partial[4][D_DIM];

    const int b = blockIdx.x;
    const int t = threadIdx.x;

    const int sid = idx[b];  // wave-uniform
    if (t < K_NBR) {
        ids[t] = indices[(size_t)sid * K_NBR + t];
        vs[t]  = values[(size_t)sid * K_NBR + t];
    }
    __syncthreads();

    const int w = t >> 6;
    const int l = t & 63;

    float acc = 0.f;
    #pragma unroll 4
    for (int k = w; k < K_NBR; k += 4) {
        const int   id = ids[k];  // uniform per wave -> broadcast
        const float v  = vs[k];
        acc += v * enc[(size_t)id * D_DIM + l];
    }
    partial[w][l] = acc;
    __syncthreads();

    if (w == 0) {
        out[(size_t)b * D_DIM + l] =
            partial[0][l] + partial[1][l] + partial[2][l] + partial[3][l];
    }
}

extern "C" void kernel_launch(void* const* d_in, const int* in_sizes, int n_in,
                              void* d_out, int out_size, void* d_ws, size_t ws_size,
                              hipStream_t stream) {
    const float* X       = (const float*)d_in[0];
    const int*   idx     = (const int*)d_in[1];
    const int*   indices = (const int*)d_in[2];
    const float* values  = (const float*)d_in[3];
    const float* W       = (const float*)d_in[4];
    const float* bias    = (const float*)d_in[5];
    float*       out     = (float*)d_out;

    const int N = in_sizes[0] / F_DIM;   // 100000
    const int B = in_sizes[1];           // 16384

    float* enc = (float*)d_ws;           // N * D_DIM floats = 25.6 MB

    const int grid1 = (N + 255) / 256;
    encode_kernel<<<grid1, 256, 0, stream>>>(X, W, bias, enc, N);

    gather_kernel<<<B, 256, 0, stream>>>(idx, indices, values, enc, out);
}

// Round 3
// 54.247 us; speedup vs baseline: 2.1240x; 2.1240x over previous
//
#include <hip/hip_runtime.h>

#define F_DIM 128
#define D_DIM 64
#define K_NBR 128

typedef _Float16 half8 __attribute__((ext_vector_type(8)));
typedef _Float16 half4 __attribute__((ext_vector_type(4)));
typedef float f32x4 __attribute__((ext_vector_type(4)));

#define XPAD 8
#define LDK (F_DIM + XPAD)   // 136 halfs per staged row (8B-aligned, bank-spread)

// ---------------------------------------------------------------------------
// Kernel 1: enc[r][d] = f16( sum_f X[r][f] * W[f][d] + b[d] )
// MFMA 16x16x32 f16. Block = 256 thr (4 waves), 256 rows/block (4 tiles of 64).
// W^T and X tile staged in LDS as f16. A/B fragments use the same k-convention
// (k = lgrp*8 + j within a 32-chunk), so any pure k-permutation in the true HW
// layout cancels between A and B.
// ---------------------------------------------------------------------------
__global__ __launch_bounds__(256) void encode_mfma(
    const float* __restrict__ X, const float* __restrict__ W,
    const float* __restrict__ bias, _Float16* __restrict__ enc, int n)
{
    __shared__ _Float16 WT[D_DIM][LDK];   // W^T: [d][f]
    __shared__ _Float16 Xs[64][LDK];      // X tile: [row][f]
    __shared__ float    bs[D_DIM];

    const int t = threadIdx.x;

    // Stage W^T (one-time): coalesced f32 reads, scattered u16 LDS writes.
    #pragma unroll
    for (int i = 0; i < (F_DIM * D_DIM) / 256; ++i) {  // 32 iters
        int lin = i * 256 + t;
        int f = lin >> 6, d = lin & 63;
        WT[d][f] = (_Float16)W[lin];
    }
    if (t < D_DIM) bs[t] = bias[t];

    const int w    = t >> 6;
    const int l    = t & 63;
    const int lrow = l & 15;
    const int lgrp = l >> 4;

    __syncthreads();

    // B fragments: b[ct][kk], col = ct*16 + lrow, k = kk*32 + lgrp*8 + j
    half8 bfr[4][4];
    #pragma unroll
    for (int ct = 0; ct < 4; ++ct)
        #pragma unroll
        for (int kk = 0; kk < 4; ++kk)
            bfr[ct][kk] = *reinterpret_cast<const half8*>(
                &WT[ct * 16 + lrow][kk * 32 + lgrp * 8]);

    const int rowbase0 = blockIdx.x * 256;

    for (int tile = 0; tile < 4; ++tile) {
        const int rb = rowbase0 + tile * 64;
        __syncthreads();
        // Stage X rows rb..rb+63 (8192 floats): float4 coalesced, f16 half4 writes.
        #pragma unroll
        for (int i = 0; i < 8; ++i) {
            int lin4 = i * 256 + t;       // float4 index; 32 float4 per row
            int row  = lin4 >> 5;
            int k4   = lin4 & 31;
            int sr   = rb + row; if (sr >= n) sr = n - 1;
            float4 x = reinterpret_cast<const float4*>(X)[(size_t)sr * 32 + k4];
            half4 h;
            h.x = (_Float16)x.x; h.y = (_Float16)x.y;
            h.z = (_Float16)x.z; h.w = (_Float16)x.w;
            *reinterpret_cast<half4*>(&Xs[row][k4 * 4]) = h;
        }
        __syncthreads();

        f32x4 acc[4] = {{0.f,0.f,0.f,0.f},{0.f,0.f,0.f,0.f},
                        {0.f,0.f,0.f,0.f},{0.f,0.f,0.f,0.f}};
        #pragma unroll
        for (int kk = 0; kk < 4; ++kk) {
            half8 a = *reinterpret_cast<const half8*>(
                &Xs[w * 16 + lrow][kk * 32 + lgrp * 8]);
            #pragma unroll
            for (int ct = 0; ct < 4; ++ct)
                acc[ct] = __builtin_amdgcn_mfma_f32_16x16x32_f16(
                    a, bfr[ct][kk], acc[ct], 0, 0, 0);
        }

        // C/D: lane holds D[row=lgrp*4+r][col=lrow] (verified mapping).
        #pragma unroll
        for (int r = 0; r < 4; ++r) {
            int row = rb + w * 16 + lgrp * 4 + r;
            if (row < n) {
                #pragma unroll
                for (int ct = 0; ct < 4; ++ct) {
                    enc[(size_t)row * D_DIM + ct * 16 + lrow] =
                        (_Float16)(acc[ct][r] + bs[ct * 16 + lrow]);
                }
            }
        }
    }
}

// ---------------------------------------------------------------------------
// Kernel 2: out[b][d] = sum_k values[idx[b]][k] * enc[indices[idx[b]][k]][d]
// One block (4 waves) per seed. enc is f16 -> 128 B per gathered row.
// ---------------------------------------------------------------------------
__global__ __launch_bounds__(256) void gather_kernel(
    const int* __restrict__ idx, const int* __restrict__ indices,
    const float* __restrict__ values, const _Float16* __restrict__ enc,
    float* __restrict__ out)
{
    __shared__ int   ids[K_NBR];
    __shared__ float vs[K_NBR];
    __shared__ float partial[4][D_DIM];

    const int b = blockIdx.x;
    const int t = threadIdx.x;

    const int sid = idx[b];
    if (t < K_NBR) {
        ids[t] = indices[(size_t)sid * K_NBR + t];
        vs[t]  = values[(size_t)sid * K_NBR + t];
    }
    __syncthreads();

    const int w = t >> 6;
    const int l = t & 63;

    float acc = 0.f;
    #pragma unroll 8
    for (int k = w; k < K_NBR; k += 4) {
        acc += vs[k] * (float)enc[(size_t)ids[k] * D_DIM + l];
    }
    partial[w][l] = acc;
    __syncthreads();

    if (w == 0) {
        out[(size_t)b * D_DIM + l] =
            partial[0][l] + partial[1][l] + partial[2][l] + partial[3][l];
    }
}

extern "C" void kernel_launch(void* const* d_in, const int* in_sizes, int n_in,
                              void* d_out, int out_size, void* d_ws, size_t ws_size,
                              hipStream_t stream) {
    const float* X       = (const float*)d_in[0];
    const int*   idx     = (const int*)d_in[1];
    const int*   indices = (const int*)d_in[2];
    const float* values  = (const float*)d_in[3];
    const float* W       = (const float*)d_in[4];
    const float* bias    = (const float*)d_in[5];
    float*       out     = (float*)d_out;

    const int N = in_sizes[0] / F_DIM;   // 100000
    const int B = in_sizes[1];           // 16384

    _Float16* enc = (_Float16*)d_ws;     // N * 64 f16 = 12.8 MB

    const int grid1 = (N + 255) / 256;   // 256 rows per block
    encode_mfma<<<grid1, 256, 0, stream>>>(X, W, bias, enc, N);

    gather_kernel<<<B, 256, 0, stream>>>(idx, indices, values, enc, out);
}

// Round 6
// 52.685 us; speedup vs baseline: 2.1870x; 1.0297x over previous
//
#include <hip/hip_runtime.h>

#define F_DIM 128
#define D_DIM 64
#define K_NBR 128

typedef _Float16 half8 __attribute__((ext_vector_type(8)));
typedef _Float16 half4 __attribute__((ext_vector_type(4)));
typedef float f32x4 __attribute__((ext_vector_type(4)));

#define XPAD 8
#define LDK (F_DIM + XPAD)   // 136 halfs per staged row (8B-aligned, bank-spread)

// ---------------------------------------------------------------------------
// Kernel 1: enc[r][d] = f16( sum_f X[r][f] * W[f][d] + b[d] )
// MFMA 16x16x32 f16. Unchanged from R3 (measured ~15 us, HBM-bound).
// ---------------------------------------------------------------------------
__global__ __launch_bounds__(256) void encode_mfma(
    const float* __restrict__ X, const float* __restrict__ W,
    const float* __restrict__ bias, _Float16* __restrict__ enc, int n)
{
    __shared__ _Float16 WT[D_DIM][LDK];   // W^T: [d][f]
    __shared__ _Float16 Xs[64][LDK];      // X tile: [row][f]
    __shared__ float    bs[D_DIM];

    const int t = threadIdx.x;

    #pragma unroll
    for (int i = 0; i < (F_DIM * D_DIM) / 256; ++i) {  // 32 iters
        int lin = i * 256 + t;
        int f = lin >> 6, d = lin & 63;
        WT[d][f] = (_Float16)W[lin];
    }
    if (t < D_DIM) bs[t] = bias[t];

    const int w    = t >> 6;
    const int l    = t & 63;
    const int lrow = l & 15;
    const int lgrp = l >> 4;

    __syncthreads();

    half8 bfr[4][4];
    #pragma unroll
    for (int ct = 0; ct < 4; ++ct)
        #pragma unroll
        for (int kk = 0; kk < 4; ++kk)
            bfr[ct][kk] = *reinterpret_cast<const half8*>(
                &WT[ct * 16 + lrow][kk * 32 + lgrp * 8]);

    const int rowbase0 = blockIdx.x * 256;

    for (int tile = 0; tile < 4; ++tile) {
        const int rb = rowbase0 + tile * 64;
        __syncthreads();
        #pragma unroll
        for (int i = 0; i < 8; ++i) {
            int lin4 = i * 256 + t;
            int row  = lin4 >> 5;
            int k4   = lin4 & 31;
            int sr   = rb + row; if (sr >= n) sr = n - 1;
            float4 x = reinterpret_cast<const float4*>(X)[(size_t)sr * 32 + k4];
            half4 h;
            h.x = (_Float16)x.x; h.y = (_Float16)x.y;
            h.z = (_Float16)x.z; h.w = (_Float16)x.w;
            *reinterpret_cast<half4*>(&Xs[row][k4 * 4]) = h;
        }
        __syncthreads();

        f32x4 acc[4] = {{0.f,0.f,0.f,0.f},{0.f,0.f,0.f,0.f},
                        {0.f,0.f,0.f,0.f},{0.f,0.f,0.f,0.f}};
        #pragma unroll
        for (int kk = 0; kk < 4; ++kk) {
            half8 a = *reinterpret_cast<const half8*>(
                &Xs[w * 16 + lrow][kk * 32 + lgrp * 8]);
            #pragma unroll
            for (int ct = 0; ct < 4; ++ct)
                acc[ct] = __builtin_amdgcn_mfma_f32_16x16x32_f16(
                    a, bfr[ct][kk], acc[ct], 0, 0, 0);
        }

        #pragma unroll
        for (int r = 0; r < 4; ++r) {
            int row = rb + w * 16 + lgrp * 4 + r;
            if (row < n) {
                #pragma unroll
                for (int ct = 0; ct < 4; ++ct) {
                    enc[(size_t)row * D_DIM + ct * 16 + lrow] =
                        (_Float16)(acc[ct][r] + bs[ct * 16 + lrow]);
                }
            }
        }
    }
}

// ---------------------------------------------------------------------------
// Kernel 2 (wide-load version): out[b][d] = sum_k vs[k] * enc[ids[k]][d]
// One block (4 waves) per seed. Each lane loads 16 B (half8): 8 lanes cover
// one 128 B enc row, so one wave-instruction fetches 8 rows (1 KB). Wave w
// owns k in [w*32, w*32+32) -> 4 fully-unrolled iterations -> 4 KB in flight
// per wave (4x the 2 B/lane version, 8x fewer VMEM instructions).
// Cross-lane reduce over the 8 row-groups via shfl_xor(8,16,32).
// ---------------------------------------------------------------------------
__global__ __launch_bounds__(256) void gather_wide(
    const int* __restrict__ idx, const int* __restrict__ indices,
    const float* __restrict__ values, const _Float16* __restrict__ enc,
    float* __restrict__ out)
{
    __shared__ int   ids[K_NBR];
    __shared__ float vs[K_NBR];
    __shared__ float partial[4][D_DIM];

    const int b = blockIdx.x;
    const int t = threadIdx.x;

    const int sid = idx[b];
    if (t < K_NBR) {
        ids[t] = indices[(size_t)sid * K_NBR + t];
        vs[t]  = values[(size_t)sid * K_NBR + t];
    }
    __syncthreads();

    const int w    = t >> 6;
    const int l    = t & 63;
    const int rsub = l >> 3;   // which row of the 8-row group
    const int dblk = l & 7;    // which 16 B slice of the row (d = dblk*8 + j)

    float acc[8] = {0.f,0.f,0.f,0.f,0.f,0.f,0.f,0.f};

    #pragma unroll
    for (int it = 0; it < 4; ++it) {
        const int   k  = w * 32 + it * 8 + rsub;
        const int   id = ids[k];   // 8 distinct LDS addrs/wave -> broadcast, free
        const float v  = vs[k];
        half8 h = *reinterpret_cast<const half8*>(
            enc + (size_t)id * D_DIM + dblk * 8);
        #pragma unroll
        for (int j = 0; j < 8; ++j)
            acc[j] += v * (float)h[j];
    }

    // Reduce over lanes sharing dblk (masks 8,16,32).
    #pragma unroll
    for (int m = 8; m < 64; m <<= 1) {
        #pragma unroll
        for (int j = 0; j < 8; ++j)
            acc[j] += __shfl_xor(acc[j], m, 64);
    }

    if (l < 8) {   // lane l holds d = l*8 + j
        #pragma unroll
        for (int j = 0; j < 8; ++j)
            partial[w][l * 8 + j] = acc[j];
    }
    __syncthreads();

    if (w == 0) {
        out[(size_t)b * D_DIM + l] =
            partial[0][l] + partial[1][l] + partial[2][l] + partial[3][l];
    }
}

extern "C" void kernel_launch(void* const* d_in, const int* in_sizes, int n_in,
                              void* d_out, int out_size, void* d_ws, size_t ws_size,
                              hipStream_t stream) {
    const float* X       = (const float*)d_in[0];
    const int*   idx     = (const int*)d_in[1];
    const int*   indices = (const int*)d_in[2];
    const float* values  = (const float*)d_in[3];
    const float* W       = (const float*)d_in[4];
    const float* bias    = (const float*)d_in[5];
    float*       out     = (float*)d_out;

    const int N = in_sizes[0] / F_DIM;   // 100000
    const int B = in_sizes[1];           // 16384

    _Float16* enc = (_Float16*)d_ws;     // N * 64 f16 = 12.8 MB

    const int grid1 = (N + 255) / 256;
    encode_mfma<<<grid1, 256, 0, stream>>>(X, W, bias, enc, N);

    gather_wide<<<B, 256, 0, stream>>>(idx, indices, values, enc, out);
}